// Round 4
// baseline (114.134 us; speedup 1.0000x reference)
//
#include <hip/hip_runtime.h>
#include <hip/hip_cooperative_groups.h>

namespace cg = cooperative_groups;

#define D_IN 512
#define EMBED 256
#define NBLK 256   // one block per CU; 32 rows of X per block

// ws layout (floats):
//   wr   @ 0      : [32][512]  — wvp in phases 1-2, rp in phases 3-4 (aliased;
//                                live ranges separated by grid.sync)
//   part @ 16384  : [256][512] — per-block t partials
// total 589,824 bytes

__global__ __launch_bounds__(512) void k_fused(
    const float* __restrict__ X,
    const float* __restrict__ W_Q,
    const float* __restrict__ W_K,
    const float* __restrict__ W_V,
    const float* __restrict__ head_w,
    const float* __restrict__ head_b,
    float* __restrict__ out,
    float* __restrict__ wr,     // [32][512]
    float* __restrict__ part)   // [256][512]
{
    cg::grid_group grid = cg::this_grid();
    const int b    = blockIdx.x;
    const int tid  = threadIdx.x;
    const int lane = tid & 63;
    const int wid  = tid >> 6;       // 0..7
    const int c0   = lane * 4;
    const int c1   = 256 + lane * 4;

    __shared__ float smemA[8][D_IN];   // per-wave partials
    __shared__ float smemB[D_IN];      // wv / t / r vectors

    // ---------------- Phase 1: wvp[b][d] = sum_{e in [8b,8b+8)} head_w[e]*W_V[e][d]
    if (b < 32) {
        float acc = 0.f;
        const int e0 = b * 8;
#pragma unroll
        for (int e = e0; e < e0 + 8; ++e)
            acc += head_w[e] * W_V[(size_t)e * D_IN + tid];
        wr[(size_t)b * D_IN + tid] = acc;
    }
    grid.sync();

    // ---------------- Phase 2: pass1 over X
    {
        float a = 0.f;
#pragma unroll 8
        for (int j = 0; j < 32; ++j) a += wr[(size_t)j * D_IN + tid];
        smemB[tid] = a;                 // wv
    }
    __syncthreads();
    {
        const float4 wv0 = *(const float4*)(smemB + c0);
        const float4 wv1 = *(const float4*)(smemB + c1);
        float4 t0 = {0.f,0.f,0.f,0.f};
        float4 t1 = {0.f,0.f,0.f,0.f};
        const int row0 = b * 32 + wid * 4;
#pragma unroll
        for (int r = 0; r < 4; ++r) {
            const float* xr = X + (size_t)(row0 + r) * D_IN;
            const float4 a4 = *(const float4*)(xr + c0);
            const float4 b4 = *(const float4*)(xr + c1);
            float p = a4.x*wv0.x + a4.y*wv0.y + a4.z*wv0.z + a4.w*wv0.w
                    + b4.x*wv1.x + b4.y*wv1.y + b4.z*wv1.z + b4.w*wv1.w;
#pragma unroll
            for (int off = 32; off >= 1; off >>= 1) p += __shfl_xor(p, off, 64);
            t0.x += p*a4.x; t0.y += p*a4.y; t0.z += p*a4.z; t0.w += p*a4.w;
            t1.x += p*b4.x; t1.y += p*b4.y; t1.z += p*b4.z; t1.w += p*b4.w;
        }
        *(float4*)(&smemA[wid][c0]) = t0;
        *(float4*)(&smemA[wid][c1]) = t1;
    }
    __syncthreads();
    {
        float s = 0.f;
#pragma unroll
        for (int w = 0; w < 8; ++w) s += smemA[w][tid];
        part[(size_t)b * D_IN + tid] = s;
    }
    grid.sync();

    // ---------------- Phase 3: blocks 0..31: t reduce, u[e], rp[b][:]
    if (b < 32) {
        float acc = 0.f;
#pragma unroll 8
        for (int p = 0; p < NBLK; ++p) acc += part[(size_t)p * D_IN + tid];
        smemB[tid] = acc;               // t
        __syncthreads();

        const int e = b * 8 + wid;
        const float4 ta = *(const float4*)(smemB + c0);
        const float4 tb = *(const float4*)(smemB + c1);
        const float4 ka = *(const float4*)(W_K + (size_t)e * D_IN + c0);
        const float4 kb = *(const float4*)(W_K + (size_t)e * D_IN + c1);
        float p = ta.x*ka.x + ta.y*ka.y + ta.z*ka.z + ta.w*ka.w
                + tb.x*kb.x + tb.y*kb.y + tb.z*kb.z + tb.w*kb.w;
#pragma unroll
        for (int off = 32; off >= 1; off >>= 1) p += __shfl_xor(p, off, 64);
        // p == u[e] in every lane of wave wid

        const float4 qa = *(const float4*)(W_Q + (size_t)e * D_IN + c0);
        const float4 qb = *(const float4*)(W_Q + (size_t)e * D_IN + c1);
        float4 ra = {p*qa.x, p*qa.y, p*qa.z, p*qa.w};
        float4 rb = {p*qb.x, p*qb.y, p*qb.z, p*qb.w};
        *(float4*)(&smemA[wid][c0]) = ra;
        *(float4*)(&smemA[wid][c1]) = rb;
        __syncthreads();

        float s = 0.f;
#pragma unroll
        for (int w = 0; w < 8; ++w) s += smemA[w][tid];
        wr[(size_t)b * D_IN + tid] = s;   // rp
    }
    grid.sync();

    // ---------------- Phase 4: pass2 over X (same rows -> L2-hot)
    {
        float acc = 0.f;
#pragma unroll 8
        for (int j = 0; j < 32; ++j) acc += wr[(size_t)j * D_IN + tid];
        smemB[tid] = acc;               // r
    }
    __syncthreads();
    {
        const float4 r0 = *(const float4*)(smemB + c0);
        const float4 r1 = *(const float4*)(smemB + c1);
        const float bb  = head_b[0];
        const int row0 = b * 32 + wid * 4;
#pragma unroll
        for (int rr = 0; rr < 4; ++rr) {
            const int row = row0 + rr;
            const float* xr = X + (size_t)row * D_IN;
            const float4 a4 = *(const float4*)(xr + c0);
            const float4 b4 = *(const float4*)(xr + c1);
            float p = a4.x*r0.x + a4.y*r0.y + a4.z*r0.z + a4.w*r0.w
                    + b4.x*r1.x + b4.y*r1.y + b4.z*r1.z + b4.w*r1.w;
#pragma unroll
            for (int off = 32; off >= 1; off >>= 1) p += __shfl_xor(p, off, 64);
            if (lane == 0) out[row] = p + bb;
        }
    }
}

// ---------------------------------------------------------------------------
extern "C" void kernel_launch(void* const* d_in, const int* in_sizes, int n_in,
                              void* d_out, int out_size, void* d_ws, size_t ws_size,
                              hipStream_t stream) {
    const float* X      = (const float*)d_in[0];
    const float* W_Q    = (const float*)d_in[1];
    const float* W_K    = (const float*)d_in[2];
    const float* W_V    = (const float*)d_in[3];
    const float* head_w = (const float*)d_in[4];
    const float* head_b = (const float*)d_in[5];
    float* out = (float*)d_out;

    float* ws   = (float*)d_ws;
    float* wr   = ws;                 // [32][512], aliased wvp/rp
    float* part = ws + 32 * D_IN;     // [256][512]

    void* args[] = {
        (void*)&X, (void*)&W_Q, (void*)&W_K, (void*)&W_V,
        (void*)&head_w, (void*)&head_b, (void*)&out,
        (void*)&wr, (void*)&part
    };
    hipLaunchCooperativeKernel((void*)k_fused, dim3(NBLK), dim3(512),
                               args, 0, stream);
}

// Round 5
// 24.629 us; speedup vs baseline: 4.6342x; 4.6342x over previous
//
#include <hip/hip_runtime.h>

#define D_IN 512
#define EMBED 256
#define NBLK 256               // streaming blocks; 32 rows/block, 4 rows/wave
#define SCALE 16777216.0f      // 2^24
#define INV_SCALE 5.9604644775390625e-08f  // 2^-24

typedef unsigned long long ull;

// ws byte layout:
//   wvp     @ 0     : float[4][512]   (8 KB)   w_v partials, 4 e-chunks
//   t_fixed @ 8192  : ull[8][512]     (32 KB)  fixed-point t, 8 copies
//   counter @ 40960 : ull             (8 B)    arrival counter
//   rp      @ 45056 : float[32][512]  (64 KB)  r partials, 32 slices
#define WS_WVP_B 0
#define WS_TFX_B 8192
#define WS_CNT_B 40960
#define WS_RP_B  45056
#define N_ZERO   4097          // t_fixed (4096 ulls) + counter (1 ull), contiguous

// ---------------------------------------------------------------------------
// K1: wvp[eg][d] = sum_{e in chunk eg} head_w[e]*W_V[e][d]; zero t_fixed+cnt.
// grid 32 = 8 col-groups x 4 e-chunks, 64 threads
// ---------------------------------------------------------------------------
__global__ __launch_bounds__(64) void k_wv(const float* __restrict__ W_V,
                                           const float* __restrict__ head_w,
                                           float* __restrict__ wvp,
                                           ull* __restrict__ zbase) {
    const int cg  = blockIdx.x & 7;
    const int eg  = blockIdx.x >> 3;
    const int col = cg * 64 + threadIdx.x;
    float acc = 0.f;
    const int e0 = eg * 64;
#pragma unroll 8
    for (int e = e0; e < e0 + 64; ++e) acc += head_w[e] * W_V[(size_t)e * D_IN + col];
    wvp[(size_t)eg * D_IN + col] = acc;

    const int g = blockIdx.x * 64 + threadIdx.x;
    for (int i = g; i < N_ZERO; i += 32 * 64) zbase[i] = 0ull;
}

// ---------------------------------------------------------------------------
// K2: pass1 over X + fused u/r tail on the last 32 arriving blocks.
//   per row i: s_i = x_i . wv ; block t-partial -> fixed-point atomics (8 copies)
//   arrival counter; arrivals 224..255 spin to 256, then slice k = arrival-224
//   computes u[8k..8k+8) = W_K[e,:].t and rp[k][:] = sum_m u[8k+m]*W_Q[8k+m,:].
// Deterministic: slice values independent of which block computes them.
// Deadlock-free without co-residency guarantees: spinners occupy <=32 CUs.
// ---------------------------------------------------------------------------
__global__ __launch_bounds__(512) void k_pass1ur(const float* __restrict__ X,
                                                 const float* __restrict__ wvp,
                                                 const float* __restrict__ W_K,
                                                 const float* __restrict__ W_Q,
                                                 ull* __restrict__ t_fixed,
                                                 ull* __restrict__ counter,
                                                 float* __restrict__ rp) {
    const int tid  = threadIdx.x;
    const int lane = tid & 63;
    const int wid  = tid >> 6;       // 0..7
    const int c0   = lane * 4;
    const int c1   = 256 + lane * 4;

    __shared__ float lds[8][D_IN];
    __shared__ float t_lds[D_IN];
    __shared__ float u_lds[8];
    __shared__ unsigned arrival_s;

    // ---- w_v from 4 partials
    float4 wv0 = {0.f,0.f,0.f,0.f}, wv1 = {0.f,0.f,0.f,0.f};
#pragma unroll
    for (int eg = 0; eg < 4; ++eg) {
        const float4 a = *(const float4*)(wvp + (size_t)eg * D_IN + c0);
        const float4 b = *(const float4*)(wvp + (size_t)eg * D_IN + c1);
        wv0.x += a.x; wv0.y += a.y; wv0.z += a.z; wv0.w += a.w;
        wv1.x += b.x; wv1.y += b.y; wv1.z += b.z; wv1.w += b.w;
    }

    // ---- stream 32 rows: s_i dot + rank-1 t accumulate
    float4 t0 = {0.f,0.f,0.f,0.f};
    float4 t1 = {0.f,0.f,0.f,0.f};
    const int row0 = blockIdx.x * 32 + wid * 4;
#pragma unroll
    for (int r = 0; r < 4; ++r) {
        const float* xr = X + (size_t)(row0 + r) * D_IN;
        const float4 a = *(const float4*)(xr + c0);
        const float4 b = *(const float4*)(xr + c1);
        float p = a.x*wv0.x + a.y*wv0.y + a.z*wv0.z + a.w*wv0.w
                + b.x*wv1.x + b.y*wv1.y + b.z*wv1.z + b.w*wv1.w;
#pragma unroll
        for (int off = 32; off >= 1; off >>= 1) p += __shfl_xor(p, off, 64);
        t0.x += p*a.x; t0.y += p*a.y; t0.z += p*a.z; t0.w += p*a.w;
        t1.x += p*b.x; t1.y += p*b.y; t1.z += p*b.z; t1.w += p*b.w;
    }
    *(float4*)(&lds[wid][c0]) = t0;
    *(float4*)(&lds[wid][c1]) = t1;
    __syncthreads();

    // ---- block-reduce t-partial, fixed-point atomic into 1-of-8 copies.
    // Keep the atomic's return value live: forces the returning form, and the
    // s_waitcnt on its use guarantees the RMW is applied at the coherence
    // point before this thread reaches the barrier below.
    {
        float s = 0.f;
#pragma unroll
        for (int w = 0; w < 8; ++w) s += lds[w][tid];
        const long long v = llrintf(s * SCALE);
        ull old = atomicAdd(&t_fixed[(size_t)(blockIdx.x & 7) * D_IN + tid], (ull)v);
        unsigned keep = (unsigned)old ^ (unsigned)(old >> 32);
        asm volatile("" :: "v"(keep));
    }
    __syncthreads();

    // ---- arrival counter (after all this block's t atomics are applied)
    if (tid == 0) arrival_s = (unsigned)atomicAdd(counter, 1ull);
    __syncthreads();
    const unsigned arrival = arrival_s;
    if (arrival < 224u) return;
    const int k = (int)arrival - 224;

    // ---- wait for all 256 blocks' t contributions
    if (tid == 0) {
        while (atomicAdd(counter, 0ull) < 256ull) __builtin_amdgcn_s_sleep(8);
    }
    __syncthreads();

    // ---- t = sum of 8 fixed copies (atomic reads: coherent)
    {
        long long acc = 0;
#pragma unroll
        for (int j = 0; j < 8; ++j)
            acc += (long long)atomicAdd(&t_fixed[(size_t)j * D_IN + tid], 0ull);
        t_lds[tid] = (float)acc * INV_SCALE;
    }
    __syncthreads();

    // ---- u[e] for e in [8k, 8k+8): wave wid computes one e
    {
        const int e = 8 * k + wid;
        const float4 ta = *(const float4*)(t_lds + c0);
        const float4 tb = *(const float4*)(t_lds + c1);
        const float4 ka = *(const float4*)(W_K + (size_t)e * D_IN + c0);
        const float4 kb = *(const float4*)(W_K + (size_t)e * D_IN + c1);
        float p = ta.x*ka.x + ta.y*ka.y + ta.z*ka.z + ta.w*ka.w
                + tb.x*kb.x + tb.y*kb.y + tb.z*kb.z + tb.w*kb.w;
#pragma unroll
        for (int off = 32; off >= 1; off >>= 1) p += __shfl_xor(p, off, 64);
        if (lane == 0) u_lds[wid] = p;
    }
    __syncthreads();

    // ---- rp[k][tid] = sum_m u[m] * W_Q[8k+m][tid]   (coalesced)
    {
        float racc = 0.f;
#pragma unroll
        for (int m = 0; m < 8; ++m)
            racc += u_lds[m] * W_Q[(size_t)(8 * k + m) * D_IN + tid];
        rp[(size_t)k * D_IN + tid] = racc;
    }
}

// ---------------------------------------------------------------------------
// K3: r = sum of 32 rp slices (LDS prelude); preds[i] = x_i . r + head_b.
// ---------------------------------------------------------------------------
__global__ __launch_bounds__(512) void k_pass2(const float* __restrict__ X,
                                               const float* __restrict__ rp,
                                               const float* __restrict__ head_b,
                                               float* __restrict__ out) {
    __shared__ float r_lds[D_IN];
    const int tid = threadIdx.x;

    float acc = 0.f;
#pragma unroll 8
    for (int j = 0; j < 32; ++j) acc += rp[(size_t)j * D_IN + tid];
    r_lds[tid] = acc;
    __syncthreads();

    const int lane = tid & 63;
    const int wid  = tid >> 6;
    const int c0   = lane * 4;
    const int c1   = 256 + lane * 4;

    const float4 r0 = *(const float4*)(r_lds + c0);
    const float4 r1 = *(const float4*)(r_lds + c1);
    const float bb  = head_b[0];

    const int row0 = blockIdx.x * 32 + wid * 4;
#pragma unroll
    for (int rr = 0; rr < 4; ++rr) {
        const int row = row0 + rr;
        const float* xr = X + (size_t)row * D_IN;
        const float4 a = *(const float4*)(xr + c0);
        const float4 b = *(const float4*)(xr + c1);
        float p = a.x*r0.x + a.y*r0.y + a.z*r0.z + a.w*r0.w
                + b.x*r1.x + b.y*r1.y + b.z*r1.z + b.w*r1.w;
#pragma unroll
        for (int off = 32; off >= 1; off >>= 1) p += __shfl_xor(p, off, 64);
        if (lane == 0) out[row] = p + bb;
    }
}

// ---------------------------------------------------------------------------
extern "C" void kernel_launch(void* const* d_in, const int* in_sizes, int n_in,
                              void* d_out, int out_size, void* d_ws, size_t ws_size,
                              hipStream_t stream) {
    const float* X      = (const float*)d_in[0];
    const float* W_Q    = (const float*)d_in[1];
    const float* W_K    = (const float*)d_in[2];
    const float* W_V    = (const float*)d_in[3];
    const float* head_w = (const float*)d_in[4];
    const float* head_b = (const float*)d_in[5];
    float* out = (float*)d_out;

    char* ws = (char*)d_ws;
    float* wvp   = (float*)(ws + WS_WVP_B);
    ull*   t_fix = (ull*)  (ws + WS_TFX_B);
    ull*   cnt   = (ull*)  (ws + WS_CNT_B);
    float* rp    = (float*)(ws + WS_RP_B);

    k_wv     <<<32,   64,  0, stream>>>(W_V, head_w, wvp, t_fix);  // zbase: t_fix..cnt
    k_pass1ur<<<NBLK, 512, 0, stream>>>(X, wvp, W_K, W_Q, t_fix, cnt, rp);
    k_pass2  <<<NBLK, 512, 0, stream>>>(X, rp, head_b, out);
}